// Round 11
// baseline (137.472 us; speedup 1.0000x reference)
//
#include <hip/hip_runtime.h>
#include <math.h>

#define EPSF 1e-7f
#define NP 4096

typedef __attribute__((ext_vector_type(8)))  short  short8;
typedef __attribute__((ext_vector_type(8)))  __bf16 bf16x8;
typedef __attribute__((ext_vector_type(16))) float  f32x16;

__device__ __forceinline__ unsigned short bf16_rn(float x) {
    unsigned int u = __float_as_uint(x);
    unsigned int r = u + 0x7FFFu + ((u >> 16) & 1u);
    return (unsigned short)(r >> 16);
}
__device__ __forceinline__ float bf16_to_f(unsigned short h) {
    return __uint_as_float(((unsigned int)h) << 16);
}

// fold 16 mfma outputs into 2 running-min accumulators (8 v_min3_f32)
__device__ __forceinline__ void fold16(const f32x16& d, float& ra, float& rb) {
    ra = fminf(fminf(d[0],  d[1]),  ra);
    rb = fminf(fminf(d[2],  d[3]),  rb);
    ra = fminf(fminf(d[4],  d[5]),  ra);
    rb = fminf(fminf(d[6],  d[7]),  rb);
    ra = fminf(fminf(d[8],  d[9]),  ra);
    rb = fminf(fminf(d[10], d[11]), rb);
    ra = fminf(fminf(d[12], d[13]), ra);
    rb = fminf(fminf(d[14], d[15]), rb);
}

// query-side (B operand) fragment (verified rounds 4-10, absmax 0.0):
// kg=0 -> [-2xh,-2yh,-2zh,-2xl,-2yl,-2zl,-2xh,-2yh] ; kg=1 -> [-2zh,1,1,0..]
__device__ __forceinline__ bf16x8 make_qfrag(float x, float y, float z, int kg) {
    float m2x = -2.f * x, m2y = -2.f * y, m2z = -2.f * z;
    unsigned short xh = bf16_rn(m2x), yh = bf16_rn(m2y), zh = bf16_rn(m2z);
    unsigned short xl = bf16_rn(m2x - bf16_to_f(xh));
    unsigned short yl = bf16_rn(m2y - bf16_to_f(yh));
    unsigned short zl = bf16_rn(m2z - bf16_to_f(zh));
    short8 s;
    if (kg == 0)
        s = short8{(short)xh,(short)yh,(short)zh,(short)xl,(short)yl,(short)zl,(short)xh,(short)yh};
    else
        s = short8{(short)zh,(short)0x3F80,(short)0x3F80,0,0,0,0,0};
    return __builtin_bit_cast(bf16x8, s);
}

// ---------------------------------------------------------------------------
// Single-dispatch VAE loss.
// grid (16 strips, 16 combos, 4 quarters) = 1024 blocks, 256 thr (4 waves),
// 32KB LDS -> 4 blocks/CU = 4 waves/SIMD (double r9's occupancy, same cheap
// fold16). Each block: build its 1024-pt db quarter panel in LDS, cross with
// its 256 queries (2 B-frags/wave) via the r9 dual-slack pipeline, write
// per-(query,quarter) min to wsmin. Cell tail (4th block of a (combo,strip)
// cell, elected by counter atomic): min over quarters + sqrt + cell sum +
// this cell's BCE/CR slice -> parts[cell]. Global tail (256th cell): sum
// parts -> out. Control-only atomics; all FP reductions fixed-order ->
// deterministic. Counters zeroed by hipMemsetAsync each call.
// ---------------------------------------------------------------------------
__global__ __launch_bounds__(256, 4) void vae_onepass(
    const float* __restrict__ pred, const float* __restrict__ targ,
    const float* __restrict__ prob_pred, const float* __restrict__ prob_target,
    const float* __restrict__ mu, const float* __restrict__ lb,
    const float* __restrict__ ub, float* __restrict__ out,
    int* __restrict__ cellcnt, int* __restrict__ gcnt,
    float* __restrict__ parts, float* __restrict__ wsmin,
    int nprob, int K)
{
    const int tid  = threadIdx.x;
    const int lane = tid & 63, w = tid >> 6, kg = lane >> 5;
    const int strip   = blockIdx.x;        // 0..15 : 256-query strip
    const int combo   = blockIdx.y;        // 0..15 : dir*8 + b
    const int quarter = blockIdx.z;        // 0..3  : 1024-pt db quarter
    const int dir = combo >> 3, b = combo & 7;
    const int cell = combo * 16 + strip;

    __shared__ char  panel[32768];         // 1024 pts x 32B (32 tiles x 1KB)
    __shared__ float red4[4];
    __shared__ int   lastflag;

    // ---- query (B operand) fragments + fp32 norms
    const float* Q = (dir ? targ : pred) + (size_t)b * NP * 3;
    const int qA = strip * 256 + w * 64 + (lane & 31);
    const int qB = qA + 32;
    const float ax = Q[qA * 3], ay = Q[qA * 3 + 1], az = Q[qA * 3 + 2];
    const float bx = Q[qB * 3], by = Q[qB * 3 + 1], bz = Q[qB * 3 + 2];
    const bf16x8 fragA = make_qfrag(ax, ay, az, kg);
    const bf16x8 fragB = make_qfrag(bx, by, bz, kg);
    const float n1A = fmaf(ax, ax, fmaf(ay, ay, az * az));
    const float n1B = fmaf(bx, bx, fmaf(by, by, bz * bz));

    // ---- build 1024-pt quarter panel in LDS (4 pts/thread)
    const float* D = (dir ? pred : targ) + ((size_t)b * NP + quarter * 1024) * 3;
#pragma unroll
    for (int i = 0; i < 4; ++i) {
        const int pt = i * 256 + tid;      // local 0..1023
        const float* dp = D + (size_t)pt * 3;
        float x = dp[0], y = dp[1], z = dp[2];
        float n2 = fmaf(x, x, fmaf(y, y, z * z));
        unsigned short xh = bf16_rn(x), yh = bf16_rn(y), zh = bf16_rn(z);
        unsigned short xl = bf16_rn(x - bf16_to_f(xh));
        unsigned short yl = bf16_rn(y - bf16_to_f(yh));
        unsigned short zl = bf16_rn(z - bf16_to_f(zh));
        unsigned short nh = bf16_rn(n2);
        unsigned short nl = bf16_rn(n2 - bf16_to_f(nh));
        short8 k0 = short8{(short)xh,(short)yh,(short)zh,
                           (short)xh,(short)yh,(short)zh,
                           (short)xl,(short)yl};
        short8 k1 = short8{(short)zl,(short)nh,(short)nl,0,0,0,0,0};
        char* base = panel + (pt >> 5) * 1024 + (pt & 31) * 16;
        *(short8*)base         = k0;
        *(short8*)(base + 512) = k1;
    }
    __syncthreads();

    // ---- 32 MFMA tiles, dual-slack software pipeline (r9 shape)
    float rA0 = 3.4e38f, rA1 = 3.4e38f, rB0 = 3.4e38f, rB1 = 3.4e38f;
    const f32x16 zero = {0.f};
    const char* ab = panel + kg * 512 + (lane & 31) * 16;

    bf16x8 a0 = *(const bf16x8*)(ab);
    bf16x8 a1 = *(const bf16x8*)(ab + 1024);
    f32x16 e0 = __builtin_amdgcn_mfma_f32_32x32x16_bf16(a0, fragA, zero, 0, 0, 0);
    f32x16 e1 = __builtin_amdgcn_mfma_f32_32x32x16_bf16(a0, fragB, zero, 0, 0, 0);
    f32x16 o0 = __builtin_amdgcn_mfma_f32_32x32x16_bf16(a1, fragA, zero, 0, 0, 0);
    f32x16 o1 = __builtin_amdgcn_mfma_f32_32x32x16_bf16(a1, fragB, zero, 0, 0, 0);
    bf16x8 a2 = *(const bf16x8*)(ab + 2048);
    bf16x8 a3 = *(const bf16x8*)(ab + 3072);

#pragma unroll 2
    for (int t = 2; t <= 28; t += 2) {
        bf16x8 a2n = *(const bf16x8*)(ab + (t + 2) * 1024);
        bf16x8 a3n = *(const bf16x8*)(ab + (t + 3) * 1024);
        fold16(e0, rA0, rA1);
        fold16(e1, rB0, rB1);
        e0 = __builtin_amdgcn_mfma_f32_32x32x16_bf16(a2, fragA, zero, 0, 0, 0);
        e1 = __builtin_amdgcn_mfma_f32_32x32x16_bf16(a2, fragB, zero, 0, 0, 0);
        fold16(o0, rA0, rA1);
        fold16(o1, rB0, rB1);
        o0 = __builtin_amdgcn_mfma_f32_32x32x16_bf16(a3, fragA, zero, 0, 0, 0);
        o1 = __builtin_amdgcn_mfma_f32_32x32x16_bf16(a3, fragB, zero, 0, 0, 0);
        a2 = a2n; a3 = a3n;
    }
    fold16(e0, rA0, rA1);
    fold16(e1, rB0, rB1);
    e0 = __builtin_amdgcn_mfma_f32_32x32x16_bf16(a2, fragA, zero, 0, 0, 0);
    e1 = __builtin_amdgcn_mfma_f32_32x32x16_bf16(a2, fragB, zero, 0, 0, 0);
    fold16(o0, rA0, rA1);
    fold16(o1, rB0, rB1);
    o0 = __builtin_amdgcn_mfma_f32_32x32x16_bf16(a3, fragA, zero, 0, 0, 0);
    o1 = __builtin_amdgcn_mfma_f32_32x32x16_bf16(a3, fragB, zero, 0, 0, 0);
    fold16(e0, rA0, rA1);
    fold16(e1, rB0, rB1);
    fold16(o0, rA0, rA1);
    fold16(o1, rB0, rB1);

    // ---- merge C-row halves, add |q|^2, write per-(query,quarter) min
    float rA = fminf(rA0, rA1);  rA = fminf(rA, __shfl_xor(rA, 32));
    float rB = fminf(rB0, rB1);  rB = fminf(rB, __shfl_xor(rB, 32));
    float val = (lane < 32) ? (rA + n1A) : (rB + n1B);
    const int q = strip * 256 + w * 64 + lane;
    wsmin[((size_t)((combo << 12) + q) << 2) + quarter] = val;

    // ---- elect cell-last block (4th quarter of this (combo,strip) cell)
    __threadfence();
    __syncthreads();
    if (tid == 0) lastflag = (atomicAdd(&cellcnt[cell], 1) == 3);
    __syncthreads();
    if (!lastflag) return;
    __threadfence();

    // ---- cell tail: min over quarters, sqrt, cell sum + BCE/CR slice
    {
        const int g = (combo << 12) + strip * 256 + tid;
        float4 v = ((const float4*)wsmin)[g];
        float m = fminf(fminf(v.x, v.y), fminf(v.z, v.w));
        float dist = sqrtf(fmaxf(m, 1e-12f));

        float bce = 0.f;
        const int ib = cell * 32 + tid;
        if (tid < 32 && ib < nprob) {
            float p = fminf(fmaxf(prob_pred[ib], EPSF), 1.0f - EPSF);
            float t = prob_target[ib];
            bce = t * logf(p) + (1.0f - t) * log1pf(-p);
        }
        float cr = 0.f;
        const int ic = cell * 4 + tid;
        if (tid < 4 && ic < K) {
            float c = fabsf(mu[ic]) - 0.5f * (lb[ic] + ub[ic]) + 1.0f / (float)K;
            cr = fmaxf(c, 0.f);
        }

        float v1 = dist + cr - bce / (float)nprob;
        for (int off = 32; off; off >>= 1) v1 += __shfl_xor(v1, off);
        if ((tid & 63) == 0) red4[tid >> 6] = v1;
        __syncthreads();
        if (tid == 0) parts[cell] = red4[0] + red4[1] + red4[2] + red4[3];
    }

    // ---- elect global-last cell (256th)
    __threadfence();
    __syncthreads();
    if (tid == 0) lastflag = (atomicAdd(gcnt, 1) == 255);
    __syncthreads();
    if (!lastflag) return;
    __threadfence();

    // ---- global tail: sum 256 parts -> out
    {
        float v1 = parts[tid];
        for (int off = 32; off; off >>= 1) v1 += __shfl_xor(v1, off);
        if ((tid & 63) == 0) red4[tid >> 6] = v1;
        __syncthreads();
        if (tid == 0) out[0] = red4[0] + red4[1] + red4[2] + red4[3];
    }
}

extern "C" void kernel_launch(void* const* d_in, const int* in_sizes, int n_in,
                              void* d_out, int out_size, void* d_ws, size_t ws_size,
                              hipStream_t stream) {
    const float* prob_pred   = (const float*)d_in[0];
    const float* prob_target = (const float*)d_in[1];
    const float* x_pred      = (const float*)d_in[2];
    const float* x_target    = (const float*)d_in[3];
    const float* mu          = (const float*)d_in[4];
    const float* lb          = (const float*)d_in[5];
    const float* ub          = (const float*)d_in[6];
    float* out = (float*)d_out;

    // ws layout: [0,1024)   256 cell counters (int)
    //            [1024,1028) global counter (int)
    //            [2048,3072) parts  (256 f32)
    //            [4096, +1MB) wsmin (16 combos x 4096 q x 4 quarters f32)
    int*   cellcnt = (int*)d_ws;
    int*   gcnt    = (int*)((char*)d_ws + 1024);
    float* parts   = (float*)((char*)d_ws + 2048);
    float* wsmin   = (float*)((char*)d_ws + 4096);

    const int nprob = in_sizes[0];      // 8000
    const int K     = in_sizes[4];      // 1000

    hipMemsetAsync(d_ws, 0, 1028, stream);   // zero counters (graph-legal)

    dim3 grid(16, 16, 4);
    vae_onepass<<<grid, 256, 0, stream>>>(
        x_pred, x_target, prob_pred, prob_target, mu, lb, ub,
        out, cellcnt, gcnt, parts, wsmin, nprob, K);
}

// Round 12
// 25.953 us; speedup vs baseline: 5.2970x; 5.2970x over previous
//
#include <hip/hip_runtime.h>
#include <math.h>

#define EPSF 1e-7f
#define NP 4096

typedef __attribute__((ext_vector_type(8)))  short  short8;
typedef __attribute__((ext_vector_type(8)))  __bf16 bf16x8;
typedef __attribute__((ext_vector_type(16))) float  f32x16;

__device__ __forceinline__ unsigned short bf16_rn(float x) {
    unsigned int u = __float_as_uint(x);
    unsigned int r = u + 0x7FFFu + ((u >> 16) & 1u);
    return (unsigned short)(r >> 16);
}
__device__ __forceinline__ float bf16_to_f(unsigned short h) {
    return __uint_as_float(((unsigned int)h) << 16);
}

// fold 16 mfma outputs into 2 running-min accumulators (8 v_min3_f32)
__device__ __forceinline__ void fold16(const f32x16& d, float& ra, float& rb) {
    ra = fminf(fminf(d[0],  d[1]),  ra);
    rb = fminf(fminf(d[2],  d[3]),  rb);
    ra = fminf(fminf(d[4],  d[5]),  ra);
    rb = fminf(fminf(d[6],  d[7]),  rb);
    ra = fminf(fminf(d[8],  d[9]),  ra);
    rb = fminf(fminf(d[10], d[11]), rb);
    ra = fminf(fminf(d[12], d[13]), ra);
    rb = fminf(fminf(d[14], d[15]), rb);
}

// query-side (B operand) fragment (verified rounds 4-11, absmax 0.0):
// kg=0 -> [-2xh,-2yh,-2zh,-2xl,-2yl,-2zl,-2xh,-2yh] ; kg=1 -> [-2zh,1,1,0..]
__device__ __forceinline__ bf16x8 make_qfrag(float x, float y, float z, int kg) {
    float m2x = -2.f * x, m2y = -2.f * y, m2z = -2.f * z;
    unsigned short xh = bf16_rn(m2x), yh = bf16_rn(m2y), zh = bf16_rn(m2z);
    unsigned short xl = bf16_rn(m2x - bf16_to_f(xh));
    unsigned short yl = bf16_rn(m2y - bf16_to_f(yh));
    unsigned short zl = bf16_rn(m2z - bf16_to_f(zh));
    short8 s;
    if (kg == 0)
        s = short8{(short)xh,(short)yh,(short)zh,(short)xl,(short)yl,(short)zl,(short)xh,(short)yh};
    else
        s = short8{(short)zh,(short)0x3F80,(short)0x3F80,0,0,0,0,0};
    return __builtin_bit_cast(bf16x8, s);
}

// ---------------------------------------------------------------------------
// Single-dispatch VAE loss, r9 chamfer body UNCHANGED (no launch_bounds cap,
// no spill): 256 blocks x 512 threads, ~131KB LDS, 1 block/CU.
// Each block: full 4096-pt db panel in LDS, dual-slack pipelined 64-tile MFMA
// loop, per-query min -> dist; block also folds in ITS slice of BCE (32
// elems) and CR (4 elems); fixed-order block sum -> parts[bid].
// Tail: one atomicAdd per block on gcnt; the 256th block (any) fences and
// sums parts[0..255] in index order -> out[0]. Deterministic (control-only
// atomic; all FP sums fixed-order). gcnt zeroed via hipMemsetAsync per call.
// ---------------------------------------------------------------------------
__global__ __launch_bounds__(512) void vae_single(
    const float* __restrict__ pred, const float* __restrict__ targ,
    const float* __restrict__ prob_pred, const float* __restrict__ prob_target,
    const float* __restrict__ mu, const float* __restrict__ lb,
    const float* __restrict__ ub, float* __restrict__ out,
    float* __restrict__ parts, int* __restrict__ gcnt,
    int nprob, int K)
{
    const int tid  = threadIdx.x;
    const int lane = tid & 63, w = tid >> 6, kg = lane >> 5;
    const int half = w >> 2;               // db half this wave scans
    const int bid  = blockIdx.x;
    const int strip = bid & 15;            // 256-query strip
    const int combo = bid >> 4;            // dir*8 + b
    const int dir = combo >> 3, b = combo & 7;

    __shared__ char  panel[131072];        // 4096 pts x 32B (128 tiles x 1KB)
    __shared__ float redbuf[512];
    __shared__ float red4[4];
    __shared__ int   lastflag;

    // ---- query (B operand) fragments + fp32 norms
    const float* Q = (dir ? targ : pred) + (size_t)b * NP * 3;
    const int qA = strip * 256 + (w & 3) * 64 + (lane & 31);
    const int qB = qA + 32;
    const float ax = Q[qA * 3], ay = Q[qA * 3 + 1], az = Q[qA * 3 + 2];
    const float bx = Q[qB * 3], by = Q[qB * 3 + 1], bz = Q[qB * 3 + 2];
    const bf16x8 fragA = make_qfrag(ax, ay, az, kg);
    const bf16x8 fragB = make_qfrag(bx, by, bz, kg);
    const float n1A = fmaf(ax, ax, fmaf(ay, ay, az * az));
    const float n1B = fmaf(bx, bx, fmaf(by, by, bz * bz));

    // ---- build full 4096-point panel in LDS (8 pts/thread)
    const float* D = (dir ? pred : targ) + (size_t)b * NP * 3;
#pragma unroll
    for (int i = 0; i < 8; ++i) {
        const int pt = i * 512 + tid;      // 0..4095
        const float* dp = D + (size_t)pt * 3;
        float x = dp[0], y = dp[1], z = dp[2];
        float n2 = fmaf(x, x, fmaf(y, y, z * z));
        unsigned short xh = bf16_rn(x), yh = bf16_rn(y), zh = bf16_rn(z);
        unsigned short xl = bf16_rn(x - bf16_to_f(xh));
        unsigned short yl = bf16_rn(y - bf16_to_f(yh));
        unsigned short zl = bf16_rn(z - bf16_to_f(zh));
        unsigned short nh = bf16_rn(n2);
        unsigned short nl = bf16_rn(n2 - bf16_to_f(nh));
        short8 k0 = short8{(short)xh,(short)yh,(short)zh,
                           (short)xh,(short)yh,(short)zh,
                           (short)xl,(short)yl};
        short8 k1 = short8{(short)zl,(short)nh,(short)nl,0,0,0,0,0};
        char* base = panel + (pt >> 5) * 1024 + (pt & 31) * 16;
        *(short8*)base         = k0;
        *(short8*)(base + 512) = k1;
    }
    __syncthreads();

    // ---- 64 MFMA tiles, dual-slack software pipeline (r9, unchanged)
    float rA0 = 3.4e38f, rA1 = 3.4e38f, rB0 = 3.4e38f, rB1 = 3.4e38f;
    const f32x16 zero = {0.f};
    const char* ab = panel + (size_t)half * 65536 + kg * 512 + (lane & 31) * 16;

    bf16x8 a0 = *(const bf16x8*)(ab);
    bf16x8 a1 = *(const bf16x8*)(ab + 1024);
    f32x16 e0 = __builtin_amdgcn_mfma_f32_32x32x16_bf16(a0, fragA, zero, 0, 0, 0);
    f32x16 e1 = __builtin_amdgcn_mfma_f32_32x32x16_bf16(a0, fragB, zero, 0, 0, 0);
    f32x16 o0 = __builtin_amdgcn_mfma_f32_32x32x16_bf16(a1, fragA, zero, 0, 0, 0);
    f32x16 o1 = __builtin_amdgcn_mfma_f32_32x32x16_bf16(a1, fragB, zero, 0, 0, 0);
    bf16x8 a2 = *(const bf16x8*)(ab + 2048);
    bf16x8 a3 = *(const bf16x8*)(ab + 3072);

#pragma unroll 2
    for (int t = 2; t <= 60; t += 2) {
        bf16x8 a2n = *(const bf16x8*)(ab + (t + 2) * 1024);
        bf16x8 a3n = *(const bf16x8*)(ab + (t + 3) * 1024);
        fold16(e0, rA0, rA1);
        fold16(e1, rB0, rB1);
        e0 = __builtin_amdgcn_mfma_f32_32x32x16_bf16(a2, fragA, zero, 0, 0, 0);
        e1 = __builtin_amdgcn_mfma_f32_32x32x16_bf16(a2, fragB, zero, 0, 0, 0);
        fold16(o0, rA0, rA1);
        fold16(o1, rB0, rB1);
        o0 = __builtin_amdgcn_mfma_f32_32x32x16_bf16(a3, fragA, zero, 0, 0, 0);
        o1 = __builtin_amdgcn_mfma_f32_32x32x16_bf16(a3, fragB, zero, 0, 0, 0);
        a2 = a2n; a3 = a3n;
    }
    fold16(e0, rA0, rA1);
    fold16(e1, rB0, rB1);
    e0 = __builtin_amdgcn_mfma_f32_32x32x16_bf16(a2, fragA, zero, 0, 0, 0);
    e1 = __builtin_amdgcn_mfma_f32_32x32x16_bf16(a2, fragB, zero, 0, 0, 0);
    fold16(o0, rA0, rA1);
    fold16(o1, rB0, rB1);
    o0 = __builtin_amdgcn_mfma_f32_32x32x16_bf16(a3, fragA, zero, 0, 0, 0);
    o1 = __builtin_amdgcn_mfma_f32_32x32x16_bf16(a3, fragB, zero, 0, 0, 0);
    fold16(e0, rA0, rA1);
    fold16(e1, rB0, rB1);
    fold16(o0, rA0, rA1);
    fold16(o1, rB0, rB1);

    // ---- merge C-row halves, add |q|^2, exchange halves through LDS
    float rA = fminf(rA0, rA1);  rA = fminf(rA, __shfl_xor(rA, 32));
    float rB = fminf(rB0, rB1);  rB = fminf(rB, __shfl_xor(rB, 32));
    float val = (lane < 32) ? (rA + n1A) : (rB + n1B);
    __syncthreads();                       // panel reads done
    redbuf[half * 256 + (w & 3) * 64 + lane] = val;
    __syncthreads();

    // ---- min over halves, sqrt, + this block's BCE/CR slice, block sum
    if (tid < 256) {
        float m = fminf(redbuf[tid], redbuf[256 + tid]);
        float v1 = sqrtf(fmaxf(m, 1e-12f));

        const int ib = bid * 32 + tid;     // 256 blocks x 32 = 8192 >= nprob
        if (tid < 32 && ib < nprob) {
            float p = fminf(fmaxf(prob_pred[ib], EPSF), 1.0f - EPSF);
            float t = prob_target[ib];
            v1 -= (t * logf(p) + (1.0f - t) * log1pf(-p)) / (float)nprob;
        }
        const int ic = bid * 4 + tid;      // 256 blocks x 4 = 1024 >= K
        if (tid < 4 && ic < K) {
            float c = fabsf(mu[ic]) - 0.5f * (lb[ic] + ub[ic]) + 1.0f / (float)K;
            v1 += fmaxf(c, 0.f);
        }

        for (int off = 32; off; off >>= 1) v1 += __shfl_xor(v1, off);
        if ((tid & 63) == 0) red4[tid >> 6] = v1;
    }
    __syncthreads();

    // ---- publish part, elect last block (single counter, single fence)
    if (tid == 0) {
        parts[bid] = red4[0] + red4[1] + red4[2] + red4[3];
        __threadfence();                          // release parts[bid]
        lastflag = (atomicAdd(gcnt, 1) == 255);
    }
    __syncthreads();
    if (!lastflag) return;

    // ---- last block: acquire, sum 256 parts in fixed order -> out
    __threadfence();
    if (tid < 256) {
        float v1 = parts[tid];
        for (int off = 32; off; off >>= 1) v1 += __shfl_xor(v1, off);
        if ((tid & 63) == 0) red4[tid >> 6] = v1;
    }
    __syncthreads();
    if (tid == 0) out[0] = red4[0] + red4[1] + red4[2] + red4[3];
}

extern "C" void kernel_launch(void* const* d_in, const int* in_sizes, int n_in,
                              void* d_out, int out_size, void* d_ws, size_t ws_size,
                              hipStream_t stream) {
    const float* prob_pred   = (const float*)d_in[0];
    const float* prob_target = (const float*)d_in[1];
    const float* x_pred      = (const float*)d_in[2];
    const float* x_target    = (const float*)d_in[3];
    const float* mu          = (const float*)d_in[4];
    const float* lb          = (const float*)d_in[5];
    const float* ub          = (const float*)d_in[6];
    float* out = (float*)d_out;

    // ws layout: [0,1024) parts (256 f32) ; [1024,1028) gcnt (int)
    float* parts = (float*)d_ws;
    int*   gcnt  = (int*)((char*)d_ws + 1024);

    const int nprob = in_sizes[0];      // 8000
    const int K     = in_sizes[4];      // 1000

    hipMemsetAsync(gcnt, 0, 4, stream);   // reset election counter (graph-legal)

    vae_single<<<256, 512, 0, stream>>>(
        x_pred, x_target, prob_pred, prob_target, mu, lb, ub,
        out, parts, gcnt, nprob, K);
}